// Round 8
// baseline (177.757 us; speedup 1.0000x reference)
//
#include <hip/hip_runtime.h>
#include <stdint.h>

#define Bb 2
#define Ss 2048
#define Dd 1024
#define Hh 8
#define Ee 128
#define KWW 16
#define Mm (Bb*Ss)   // 4096
#define Kk 1024      // K for both GEMMs

typedef unsigned short u16;
typedef __attribute__((ext_vector_type(8))) _Float16 f16x8;  // 8 fp16 (4 VGPRs)
typedef __attribute__((ext_vector_type(4))) float f32x4;

// fp32 -> fp16 (RTN)
__device__ __forceinline__ u16 f2h(float f) {
  union { _Float16 h; u16 u; } v; v.h = (_Float16)f; return v.u;
}
__device__ __forceinline__ float h2f(u16 u) {
  union { u16 u; _Float16 h; } v; v.u = u; return (float)v.h;
}
__device__ __forceinline__ float h2f_lo(uint32_t w) { return h2f((u16)(w & 0xFFFF)); }
__device__ __forceinline__ float h2f_hi(uint32_t w) { return h2f((u16)(w >> 16)); }

// ---------------- FRAGMENT-MAJOR layout (both GEMM operands) ----------------
// For any [rows][K=1024] f16 matrix, panels of 128 rows:
//   idx(r, k) = (r>>7)*131072 + (k>>3)*1024 + (r&127)*8 + (k&7)
// A consumer (lane fr=lane&15, q=lane>>4; window w of 32 k): reads 16B at
//   panel + (w*4+q)*1024 + (row)*8   — one global_load_dwordx4 per fragment.
// Same formula the weight panels (wT/woT) already use. R14: x and attn-out are
// ALSO emitted in this layout, so BOTH GEMMs are barrier-free and LDS-free:
// every wave streams fragments straight from L2 to VGPRs. Rationale: R5-R13
// showed MfmaUtil 21% / VALUBusy 24% / Occupancy 14% and duration INVARIANT
// across 2-deep, 3-deep-counted-vmcnt, and L2-tiled variants — the common
// element was barrier-lockstep LDS staging (~1 runnable wave/SIMD). Removing
// the barriers removes the lockstep.

// ---------------- fused prep kernel ----------------
// blocks [0,2048): x [m][d] f32 -> xf frag-major f16 (64m x 32d tile per block)
// blocks [2048,5120): Wq/Wk/Wv [h][D][E] -> wT[z] frag-major, z=proj*8+h
// blocks [5120,6144): Wo [h*E][D] -> woT[nb] frag-major over n=D
__global__ __launch_bounds__(256) void prep(
    const float* __restrict__ x, const float* __restrict__ Wq,
    const float* __restrict__ Wk, const float* __restrict__ Wv,
    const float* __restrict__ Wo,
    u16* __restrict__ xf, u16* __restrict__ wT, u16* __restrict__ woT) {
  const int bid = blockIdx.x;
  const int tid = threadIdx.x;
  if (bid < 2048) {
    // 64 m-tiles(64) x 32 d-tiles(32). thread: ml = tid&63, dg = tid>>6.
    const int m0 = (bid >> 5) * 64, d0 = (bid & 31) * 32;
    const int ml = tid & 63, dg = tid >> 6;
    const int m = m0 + ml;
    const float* src = x + (size_t)m * Dd + d0 + dg * 8;
    float4 f0 = ((const float4*)src)[0];
    float4 f1 = ((const float4*)src)[1];
    uint4 o;
    o.x = (uint32_t)f2h(f0.x) | ((uint32_t)f2h(f0.y) << 16);
    o.y = (uint32_t)f2h(f0.z) | ((uint32_t)f2h(f0.w) << 16);
    o.z = (uint32_t)f2h(f1.x) | ((uint32_t)f2h(f1.y) << 16);
    o.w = (uint32_t)f2h(f1.z) | ((uint32_t)f2h(f1.w) << 16);
    // frag-major: consecutive ml -> contiguous 16B; 1KB per wave-store
    *(uint4*)(xf + ((size_t)(m >> 7) << 17) + (size_t)((d0 >> 3) + dg) * 1024 +
              (size_t)(m & 127) * 8) = o;
    return;
  }
  __shared__ float tile[32][33];  // +1 pad: bank-conflict-free
  const int tx = tid & 31, ty = tid >> 5;  // (32,8) shape
  if (bid < 2048 + 3072) {
    const int idx = bid - 2048;
    const int z = idx >> 7, rem = idx & 127;
    const int h = z & 7;
    const float* W = (z < 8) ? Wq : (z < 16) ? Wk : Wv;
    const float* ib = W + (size_t)h * Dd * Ee;
    u16* ob = wT + (size_t)z * Ee * Kk;   // 131072 elems = [kc 128][n 128][8]
    const int r0 = (rem & 31) * 32, c0 = (rem >> 5) * 32;  // r over D(=k), c over E(=n)
    #pragma unroll
    for (int kq = 0; kq < 4; kq++)
      tile[ty + 8*kq][tx] = ib[(size_t)(r0 + ty + 8*kq) * Ee + (c0 + tx)];
    __syncthreads();
    const int k = r0 + tx;
    #pragma unroll
    for (int kq = 0; kq < 4; kq++) {
      const int n = c0 + ty + 8*kq;
      ob[(((size_t)(k >> 3) * 128 + n) << 3) + (k & 7)] = f2h(tile[tx][ty + 8*kq]);
    }
  } else {
    const int idx = bid - (2048 + 3072);
    const int r0 = (idx & 31) * 32, c0 = (idx >> 5) * 32;  // r over h*E(=k), c over D(=n)
    const int C = Dd;
    #pragma unroll
    for (int kq = 0; kq < 4; kq++)
      tile[ty + 8*kq][tx] = Wo[(size_t)(r0 + ty + 8*kq) * C + (c0 + tx)];
    __syncthreads();
    const int k = r0 + tx;
    #pragma unroll
    for (int kq = 0; kq < 4; kq++) {
      const int n = c0 + ty + 8*kq;
      woT[(size_t)(n >> 7) * 131072 +
          (((size_t)(k >> 3) * 128 + (n & 127)) << 3) + (k & 7)] = f2h(tile[tx][ty + 8*kq]);
    }
  }
}

// ---------------- barrier-free per-wave GEMM core ----------------
// Wave computes (MI*16) x (NI*16) output from frag-major A and B panels.
// No LDS, no __syncthreads: 16 MFMA per 32-k window, 1KB coalesced frag loads,
// compiler free to hoist loads across windows (unroll 4).
template<int MI, int NI>
__device__ __forceinline__ void wave_gemm(
    const u16* __restrict__ Af, const u16* __restrict__ Bf,
    int m0, int n0, f32x4 (&acc)[MI][NI]) {
  const int lane = threadIdx.x & 63;
  const int fr = lane & 15, q = lane >> 4;
  const u16* ap = Af + ((size_t)(m0 >> 7) << 17) + (size_t)q * 1024 +
                  (size_t)((m0 & 127) + fr) * 8;
  const u16* bp = Bf + (size_t)q * 1024 + (size_t)(n0 + fr) * 8;
  #pragma unroll
  for (int i = 0; i < MI; i++)
    #pragma unroll
    for (int j = 0; j < NI; j++)
      #pragma unroll
      for (int r = 0; r < 4; r++) acc[i][j][r] = 0.f;
  #pragma unroll 4
  for (int w = 0; w < Kk / 32; w++) {
    f16x8 av[MI], bv[NI];
    #pragma unroll
    for (int i = 0; i < MI; i++)
      av[i] = *(const f16x8*)(ap + (size_t)w * 4096 + i * 128);
    #pragma unroll
    for (int j = 0; j < NI; j++)
      bv[j] = *(const f16x8*)(bp + (size_t)w * 4096 + j * 128);
    #pragma unroll
    for (int i = 0; i < MI; i++)
      #pragma unroll
      for (int j = 0; j < NI; j++)
        acc[i][j] = __builtin_amdgcn_mfma_f32_16x16x32_f16(av[i], bv[j], acc[i][j], 0, 0, 0);
  }
}

// C/D layout (measured m89/m91): col = lane&15, row = (lane>>4)*4 + reg

// XCD-tiled mapping kept from R12 (XCD t owns 8 m-panels x 12 z: ~5MB L2 set).
// Block = 4 independent waves covering the 128x128 tile in 64x64 quadrants.
__global__ __launch_bounds__(256) void gemm_qkv(
    const u16* __restrict__ xf, const u16* __restrict__ wT,
    const float* __restrict__ bq, const float* __restrict__ bk, const float* __restrict__ bv,
    u16* __restrict__ q, u16* __restrict__ k, u16* __restrict__ v) {
  const int wg = blockIdx.x;             // [0,768)
  const int xcd = wg & 7;
  const int local = wg >> 3;             // [0,96)
  const int m_l = local & 7;             // 8 m-panels per tile
  const int z_l = local >> 3;            // 12 z-panels per tile
  const int m0b = (((xcd & 3) * 8) + m_l) * 128;
  const int z = (xcd >> 2) * 12 + z_l;   // proj*8 + h
  const int proj = z >> 3, h = z & 7;
  const int wv = threadIdx.x >> 6;
  const int m0 = m0b + (wv >> 1) * 64;
  const int n0 = (wv & 1) * 64;
  f32x4 acc[4][4];
  wave_gemm<4, 4>(xf, wT + ((size_t)z << 17), m0, n0, acc);

  u16* dst = proj == 0 ? q : (proj == 1 ? k : v);
  const float* bias = proj == 0 ? bq : (proj == 1 ? bk : bv);
  const int lane = threadIdx.x & 63;
  const int cn = lane & 15, rq4 = (lane >> 4) * 4;
  #pragma unroll
  for (int j = 0; j < 4; j++) {
    const int e = n0 + j * 16 + cn;
    const float bb = bias[h * Ee + e];
    #pragma unroll
    for (int i = 0; i < 4; i++) {
      #pragma unroll
      for (int r = 0; r < 4; r++) {
        const int m = m0 + i * 16 + rq4 + r;          // m = b*S + s
        const int b = m >> 11, s = m & (Ss - 1);
        dst[(((size_t)(b * Hh + h)) * Ss + s) * Ee + e] = f2h(acc[i][j][r] + bb);
      }
    }
  }
}

// gemm_out: grid (64, 8), 4 waves/block, wave tile 64m x 32n -> 2048 waves.
__global__ __launch_bounds__(256) void gemm_out(
    const u16* __restrict__ attnf, const u16* __restrict__ woT,
    const float* __restrict__ bo, float* __restrict__ out) {
  const int wv = threadIdx.x >> 6;
  const int m0 = blockIdx.x * 64;
  const int n0g = blockIdx.y * 128 + wv * 32;   // global n over D
  const int nb = n0g >> 7;
  const int n0 = n0g & 127;
  f32x4 acc[4][2];
  wave_gemm<4, 2>(attnf, woT + ((size_t)nb << 17), m0, n0, acc);
  const int lane = threadIdx.x & 63;
  const int cn = lane & 15, rq4 = (lane >> 4) * 4;
  #pragma unroll
  for (int j = 0; j < 2; j++) {
    const int n = n0g + j * 16 + cn;
    const float bb = bo[n];
    #pragma unroll
    for (int i = 0; i < 4; i++) {
      #pragma unroll
      for (int r = 0; r < 4; r++) {
        const int m = m0 + i * 16 + rq4 + r;
        out[(size_t)m * Dd + n] = acc[i][j][r] + bb;
      }
    }
  }
}

// ---------------- attention: 4 s per wave (16-lane groups), dwordx4 loads ----------------
// Each wave = four 16-lane groups, one (b,h,s) each; lane lx owns elements
// e0 = lx*8 .. +7 (16B dwordx4 per row). V rows loaded in j-order (group-uniform
// pos -> coalesced); weights redistributed via gj[j] = __shfl(w, gbase|j).
// R14: output written FRAG-MAJOR (index remap only) so gemm_out needs no LDS.
__global__ __launch_bounds__(256) void attn_kernel(
    const u16* __restrict__ q, const u16* __restrict__ k, const u16* __restrict__ v,
    const float* __restrict__ bk, const float* __restrict__ bv,
    const int* __restrict__ dil, u16* __restrict__ attnf) {
  const int nblk = (Bb * Hh * Ss) / 16;           // 2048 blocks, 4 waves x 4 s
  const int blk = (blockIdx.x & 7) * (nblk / 8) + (blockIdx.x >> 3);
  const int wid = blk * 4 + (threadIdx.x >> 6);   // [0, 8192)
  const int lane = threadIdx.x & 63;
  const int grp = lane >> 4;                       // which s of this wave's 4
  const int lx = lane & 15;                        // lane within 16-group
  const int idx = wid * 4 + grp;                   // global (b,h,s) task
  const int s = idx & (Ss - 1);
  const int bh = idx >> 11;                        // b*H + h
  const int h = bh & 7, b = bh >> 3;
  const int d = dil[h];
  const size_t base = (size_t)bh * Ss * Ee;        // u16 elements
  const u16* kp = k + base;
  const u16* vp = v + base;
  const int e0 = lx * 8;
  const int off = (d * (KWW - 1)) >> 1;

  // q slice -> f32
  float qf[8];
  {
    uint4 qw = *(const uint4*)(q + base + (size_t)s * Ee + e0);
    qf[0] = h2f_lo(qw.x); qf[1] = h2f_hi(qw.x);
    qf[2] = h2f_lo(qw.y); qf[3] = h2f_hi(qw.y);
    qf[4] = h2f_lo(qw.z); qf[5] = h2f_hi(qw.z);
    qf[6] = h2f_lo(qw.w); qf[7] = h2f_hi(qw.w);
  }
  // bias slices (padded key/value = bias projection of zero-embedding)
  float bkf[8], bvf[8];
  {
    const float4 a0 = ((const float4*)(bk + h * Ee + e0))[0];
    const float4 a1 = ((const float4*)(bk + h * Ee + e0))[1];
    bkf[0]=a0.x; bkf[1]=a0.y; bkf[2]=a0.z; bkf[3]=a0.w;
    bkf[4]=a1.x; bkf[5]=a1.y; bkf[6]=a1.z; bkf[7]=a1.w;
    const float4 c0 = ((const float4*)(bv + h * Ee + e0))[0];
    const float4 c1 = ((const float4*)(bv + h * Ee + e0))[1];
    bvf[0]=c0.x; bvf[1]=c0.y; bvf[2]=c0.z; bvf[3]=c0.w;
    bvf[4]=c1.x; bvf[5]=c1.y; bvf[6]=c1.z; bvf[7]=c1.w;
  }
  float blog = 0.f;
  #pragma unroll
  for (int i = 0; i < 8; i++) blog += qf[i] * bkf[i];
  // packed f16 v-bias for OOB substitution at load time
  uint4 bvh;
  bvh.x = (uint32_t)f2h(bvf[0]) | ((uint32_t)f2h(bvf[1]) << 16);
  bvh.y = (uint32_t)f2h(bvf[2]) | ((uint32_t)f2h(bvf[3]) << 16);
  bvh.z = (uint32_t)f2h(bvf[4]) | ((uint32_t)f2h(bvf[5]) << 16);
  bvh.w = (uint32_t)f2h(bvf[6]) | ((uint32_t)f2h(bvf[7]) << 16);

  // ---- logit partials: lane lx holds partial (over its 8 elems) for ALL 16 j ----
  float logit[KWW];
  #pragma unroll
  for (int j = 0; j < KWW; j++) {
    const int pos = s + d * j - off;
    const int posc = min(max(pos, 0), Ss - 1);
    uint4 kw = *(const uint4*)(kp + (size_t)posc * Ee + e0);
    float t = qf[0] * h2f_lo(kw.x) + qf[1] * h2f_hi(kw.x)
            + qf[2] * h2f_lo(kw.y) + qf[3] * h2f_hi(kw.y)
            + qf[4] * h2f_lo(kw.z) + qf[5] * h2f_hi(kw.z)
            + qf[6] * h2f_lo(kw.w) + qf[7] * h2f_hi(kw.w);
    logit[j] = (pos >= 0 && pos < Ss) ? t : blog;
  }

  // ---- preload v rows in j order (pos group-uniform -> coalesced 256B/group) ----
  uint4 vrow[KWW];
  #pragma unroll
  for (int j = 0; j < KWW; j++) {
    const int pos = s + d * j - off;
    const int posc = min(max(pos, 0), Ss - 1);
    uint4 vw = *(const uint4*)(vp + (size_t)posc * Ee + e0);
    const bool ok = (pos >= 0) && (pos < Ss);
    vrow[j].x = ok ? vw.x : bvh.x;
    vrow[j].y = ok ? vw.y : bvh.y;
    vrow[j].z = ok ? vw.z : bvh.z;
    vrow[j].w = ok ? vw.w : bvh.w;
  }

  // ---- reduce-scatter within 16-lane groups: lane lx ends owning logit j = lx ----
  {
    const bool hi = (lx & 8) != 0;
    #pragma unroll
    for (int jj = 0; jj < 8; jj++) {
      float send = hi ? logit[jj] : logit[jj + 8];
      float recv = __shfl_xor(send, 8, 64);
      logit[jj] = (hi ? logit[jj + 8] : logit[jj]) + recv;
    }
  }
  {
    const bool hi = (lx & 4) != 0;
    #pragma unroll
    for (int jj = 0; jj < 4; jj++) {
      float send = hi ? logit[jj] : logit[jj + 4];
      float recv = __shfl_xor(send, 4, 64);
      logit[jj] = (hi ? logit[jj + 4] : logit[jj]) + recv;
    }
  }
  {
    const bool hi = (lx & 2) != 0;
    #pragma unroll
    for (int jj = 0; jj < 2; jj++) {
      float send = hi ? logit[jj] : logit[jj + 2];
      float recv = __shfl_xor(send, 2, 64);
      logit[jj] = (hi ? logit[jj + 2] : logit[jj]) + recv;
    }
  }
  float own;
  {
    const bool hi = (lx & 1) != 0;
    float send = hi ? logit[0] : logit[1];
    float recv = __shfl_xor(send, 1, 64);
    own = (hi ? logit[1] : logit[0]) + recv;   // own = full logit for j = lx
  }

  // ---- softmax over the 16 j's (one per lane in the group) ----
  float mx = own;
  mx = fmaxf(mx, __shfl_xor(mx, 1, 64));
  mx = fmaxf(mx, __shfl_xor(mx, 2, 64));
  mx = fmaxf(mx, __shfl_xor(mx, 4, 64));
  mx = fmaxf(mx, __shfl_xor(mx, 8, 64));
  float w = __expf(own - mx);
  float sum = w;
  sum += __shfl_xor(sum, 1, 64);
  sum += __shfl_xor(sum, 2, 64);
  sum += __shfl_xor(sum, 4, 64);
  sum += __shfl_xor(sum, 8, 64);
  w *= 1.0f / (sum * 11.313708498984760f);  // /Z /sqrt(E), post-softmax quirk

  // ---- gather per-j weights: gj[j] = w of lane (gbase+j); uniform-index bpermute ----
  const int gbase = lane & 48;
  float gj[KWW];
  #pragma unroll
  for (int j = 0; j < KWW; j++)
    gj[j] = __shfl(w, gbase | j, 64);

  // ---- PV: acc_e = sum_j gj[j] * v[j][e] ----
  float acc[8];
  #pragma unroll
  for (int i = 0; i < 8; i++) acc[i] = 0.f;
  #pragma unroll
  for (int j = 0; j < KWW; j++) {
    const float wt = gj[j];
    acc[0] += wt * h2f_lo(vrow[j].x);
    acc[1] += wt * h2f_hi(vrow[j].x);
    acc[2] += wt * h2f_lo(vrow[j].y);
    acc[3] += wt * h2f_hi(vrow[j].y);
    acc[4] += wt * h2f_lo(vrow[j].z);
    acc[5] += wt * h2f_hi(vrow[j].z);
    acc[6] += wt * h2f_lo(vrow[j].w);
    acc[7] += wt * h2f_hi(vrow[j].w);
  }

  // write fp16 attn FRAG-MAJOR: row m = b*S+s, col = h*128+e0
  uint4 o;
  o.x = (uint32_t)f2h(acc[0]) | ((uint32_t)f2h(acc[1]) << 16);
  o.y = (uint32_t)f2h(acc[2]) | ((uint32_t)f2h(acc[3]) << 16);
  o.z = (uint32_t)f2h(acc[4]) | ((uint32_t)f2h(acc[5]) << 16);
  o.w = (uint32_t)f2h(acc[6]) | ((uint32_t)f2h(acc[7]) << 16);
  const int m = b * Ss + s;
  *(uint4*)(attnf + ((size_t)(m >> 7) << 17) + (size_t)(h * 16 + lx) * 1024 +
            (size_t)(m & 127) * 8) = o;
}

// ---------------- launcher ----------------
extern "C" void kernel_launch(void* const* d_in, const int* in_sizes, int n_in,
                              void* d_out, int out_size, void* d_ws, size_t ws_size,
                              hipStream_t stream) {
  (void)in_sizes; (void)n_in; (void)out_size; (void)ws_size;
  const float* x  = (const float*)d_in[0];
  const float* Wq = (const float*)d_in[1];
  const float* bq = (const float*)d_in[2];
  const float* Wk = (const float*)d_in[3];
  const float* bk = (const float*)d_in[4];
  const float* Wv = (const float*)d_in[5];
  const float* bv = (const float*)d_in[6];
  const float* Wo = (const float*)d_in[7];
  const float* bo = (const float*)d_in[8];
  const int* dil  = (const int*)d_in[9];
  float* out = (float*)d_out;

  char* ws = (char*)d_ws;
  u16* xf  = (u16*)ws;  ws += (size_t)Mm * Kk * 2;             // 8 MB  frag-major x
  u16* wT  = (u16*)ws;  ws += (size_t)24 * Ee * Kk * 2;        // 6 MB  frag-major [z]
  u16* woT = (u16*)ws;  ws += (size_t)Kk * Dd * 2;             // 2 MB  frag-major [nb]
  u16* q = (u16*)ws; ws += (size_t)Bb * Hh * Ss * Ee * 2;      // 8 MB each, f16 [bh][s][e]
  u16* k = (u16*)ws; ws += (size_t)Bb * Hh * Ss * Ee * 2;
  u16* v = (u16*)ws; ws += (size_t)Bb * Hh * Ss * Ee * 2;
  // attn frag-major (8 MB) aliases xf — dead after gemm_qkv (stream-ordered)
  u16* attnf = xf;

  prep<<<6144, 256, 0, stream>>>(x, Wq, Wk, Wv, Wo, xf, wT, woT);
  gemm_qkv<<<768, 256, 0, stream>>>(xf, wT, bq, bk, bv, q, k, v);
  attn_kernel<<<(Bb * Hh * Ss) / 16, 256, 0, stream>>>(q, k, v, bk, bv, dil, attnf);
  gemm_out<<<dim3(Mm / 64, Dd / 128), 256, 0, stream>>>(attnf, woT, bo, out);
}

// Round 9
// 157.405 us; speedup vs baseline: 1.1293x; 1.1293x over previous
//
#include <hip/hip_runtime.h>
#include <stdint.h>

#define Bb 2
#define Ss 2048
#define Dd 1024
#define Hh 8
#define Ee 128
#define KWW 16
#define Mm (Bb*Ss)   // 4096
#define Kk 1024      // K for both GEMMs

typedef unsigned short u16;
typedef __attribute__((ext_vector_type(8))) _Float16 f16x8;  // 8 fp16 (4 VGPRs)
typedef __attribute__((ext_vector_type(4))) float f32x4;

// fp32 -> fp16 (RTN)
__device__ __forceinline__ u16 f2h(float f) {
  union { _Float16 h; u16 u; } v; v.h = (_Float16)f; return v.u;
}
__device__ __forceinline__ float h2f(u16 u) {
  union { u16 u; _Float16 h; } v; v.u = u; return (float)v.h;
}
__device__ __forceinline__ float h2f_lo(uint32_t w) { return h2f((u16)(w & 0xFFFF)); }
__device__ __forceinline__ float h2f_hi(uint32_t w) { return h2f((u16)(w >> 16)); }

// async global->LDS, 16B per lane. LDS dst must be wave-uniform base; HW scatters lane*16B.
__device__ __forceinline__ void gll16(const void* g, void* l) {
  __builtin_amdgcn_global_load_lds((const __attribute__((address_space(1))) void*)g,
                                   (__attribute__((address_space(3))) void*)l, 16, 0, 0);
}

// ---------------- fused prep kernel ----------------
// Weights are emitted FRAGMENT-MAJOR: [kc][n][8] per panel (kc = k/8), so the
// GEMM B-operand is loaded straight from global as per-lane b128 (no LDS for B).
// blocks [0,4096): cast x f32->f16
// blocks [4096,7168): Wq/Wk/Wv [h][D][E] -> wT[z][kc][n(E)][8], z=proj*8+h
// blocks [7168,8192): Wo [h*E][D] -> woT[nb][kc][nn][8], n = nb*128+nn over D
__global__ __launch_bounds__(256) void prep(
    const float* __restrict__ x, const float* __restrict__ Wq,
    const float* __restrict__ Wk, const float* __restrict__ Wv,
    const float* __restrict__ Wo,
    u16* __restrict__ xh, u16* __restrict__ wT, u16* __restrict__ woT) {
  const int bid = blockIdx.x;
  const int tid = threadIdx.x;
  if (bid < 4096) {
    int i = (bid * 256 + tid) * 4;
    float4 f = *(const float4*)(x + i);
    uint64_t pk = (uint64_t)f2h(f.x) | ((uint64_t)f2h(f.y) << 16) |
                  ((uint64_t)f2h(f.z) << 32) | ((uint64_t)f2h(f.w) << 48);
    *(uint64_t*)(xh + i) = pk;
    return;
  }
  __shared__ float tile[32][33];  // +1 pad: bank-conflict-free
  const int tx = tid & 31, ty = tid >> 5;  // (32,8) shape
  if (bid < 4096 + 3072) {
    const int idx = bid - 4096;
    const int z = idx >> 7, rem = idx & 127;
    const int h = z & 7;
    const float* W = (z < 8) ? Wq : (z < 16) ? Wk : Wv;
    const float* ib = W + (size_t)h * Dd * Ee;
    u16* ob = wT + (size_t)z * Ee * Kk;   // 131072 elems = [kc 128][n 128][8]
    const int r0 = (rem & 31) * 32, c0 = (rem >> 5) * 32;  // r over D(=k), c over E(=n)
    #pragma unroll
    for (int kq = 0; kq < 4; kq++)
      tile[ty + 8*kq][tx] = ib[(size_t)(r0 + ty + 8*kq) * Ee + (c0 + tx)];
    __syncthreads();
    const int k = r0 + tx;
    #pragma unroll
    for (int kq = 0; kq < 4; kq++) {
      const int n = c0 + ty + 8*kq;
      ob[(((size_t)(k >> 3) * 128 + n) << 3) + (k & 7)] = f2h(tile[tx][ty + 8*kq]);
    }
  } else {
    const int idx = bid - (4096 + 3072);
    const int r0 = (idx & 31) * 32, c0 = (idx >> 5) * 32;  // r over h*E(=k), c over D(=n)
    const int C = Dd;
    #pragma unroll
    for (int kq = 0; kq < 4; kq++)
      tile[ty + 8*kq][tx] = Wo[(size_t)(r0 + ty + 8*kq) * C + (c0 + tx)];
    __syncthreads();
    const int k = r0 + tx;
    #pragma unroll
    for (int kq = 0; kq < 4; kq++) {
      const int n = c0 + ty + 8*kq;
      woT[(size_t)(n >> 7) * 131072 +
          (((size_t)(k >> 3) * 128 + (n & 127)) << 3) + (k & 7)] = f2h(tile[tx][ty + 8*kq]);
    }
  }
}

// ---------------- GEMM core: MTx(NJ*32) tile, BK=64, 4 waves, 16x16x32 f16 MFMA ----------------
// A: [M][K] f16 row-major -> global_load_lds into XOR-swizzled LDS, DOUBLE-BUFFERED:
//    stage A(w+1) into buf^1 while MFMAs consume buf^0; ONE barrier per iteration.
//    Swizzle: chunk p = row*8 + pc holds A[row][((pc ^ (row&7))*8) .. +7] (conflicts=0, R5).
// B: fragment-major global [kc][n][8] — per-lane b128 loads straight to VGPRs,
//    register-double-buffered one iteration ahead. NJ = n-frags per wave (wave
//    n-extent NJ*16; block n-extent NJ*32 via 2x2 wave grid).
// R15: NJ template param added so gemm_qkv can halve its N-tile (128->64) and
//    DOUBLE THE GRID: every R5-R14 structure was stuck at ~43us with Occupancy
//    14% — grid 768 = 3 blocks/CU = 3 waves/SIMD, launch-geometry-limited. At
//    1536 blocks (5/CU, LDS-capped) there are 20 waves/CU to hide the
//    latency-bound window. Inner structure byte-identical to R7/R10/R12 best.
// As points to 2*MT*64 u16 of LDS (two buffers).
template<int MT, int NJ>   // MT: 128|64 rows; NJ: 4|2 n-frags/wave
__device__ __forceinline__ void gemm_core(
    const u16* __restrict__ A, const u16* __restrict__ Btf,
    u16* As, f32x4 (&acc)[MT / 32][NJ]) {
  constexpr int MI = MT / 32;
  const int tid = threadIdx.x;
  const int wave = tid >> 6;
  const int lane = tid & 63;
  // lane l -> row +(l>>3), chunk col pc = l&7, logical col lc = pc ^ (l>>3)
  const size_t lnoff = (size_t)(lane >> 3) * Kk + (size_t)(((lane & 7) ^ (lane >> 3)) * 8);

  const int wm = (wave >> 1) * (MT / 2);  // wave 2x2 arrangement
  const int wn = (wave & 1) * (NJ * 16);
  const int fr = lane & 15;            // A: m-in-16 / B: n-in-16
  const int q  = lane >> 4;            // k quad: holds k = kwin*32 + q*8 .. +7
  const int sw = fr & 7;               // row-swizzle for A frag reads

  // B frag pointer: elem offset kc*1024 + n*8, kc = kt/8 + ks*4 + q (q folded in)
  const u16* bptr = Btf + ((size_t)q * 128 + wn + fr) * 8;
  f16x8 bcur[2 * NJ], bnxt[2 * NJ];
  #pragma unroll
  for (int ks = 0; ks < 2; ks++)
    #pragma unroll
    for (int j = 0; j < NJ; j++)
      bcur[ks * NJ + j] = *(const f16x8*)(bptr + (ks * 4) * 1024 + j * 128);

  #pragma unroll
  for (int i = 0; i < MI; i++)
    #pragma unroll
    for (int j = 0; j < NJ; j++)
      #pragma unroll
      for (int r = 0; r < 4; r++) acc[i][j][r] = 0.0f;

  // prologue: stage window 0 into buf0 (latency exposed once)
  #pragma unroll
  for (int c = 0; c < MI; c++)
    gll16(A + lnoff + (size_t)((c * 4 + wave) * 8) * Kk, As + (c * 4 + wave) * 512);
  __syncthreads();

  for (int w = 0; w < Kk / 64; w++) {
    const int kt = w * 64;
    u16* cur = As + (w & 1) * (MT * 64);
    u16* nxt = As + ((w + 1) & 1) * (MT * 64);
    // stage next A window (overlaps with compute below; drained at loop-end barrier)
    if (w + 1 < Kk / 64) {
      #pragma unroll
      for (int c = 0; c < MI; c++)
        gll16(A + lnoff + (size_t)((c * 4 + wave) * 8) * Kk + kt + 64, nxt + (c * 4 + wave) * 512);
    }
    // prefetch next B window into regs (wrap on last iter; values unused)
    const int ktn = (kt + 64) & (Kk - 1);
    #pragma unroll
    for (int ks = 0; ks < 2; ks++)
      #pragma unroll
      for (int j = 0; j < NJ; j++)
        bnxt[ks * NJ + j] = *(const f16x8*)(bptr + ((ktn >> 3) + ks * 4) * 1024 + j * 128);
    // compute current window
    #pragma unroll
    for (int ks = 0; ks < 2; ks++) {
      const int col = ((ks << 2) | q) ^ sw;   // phys 16B-chunk column (A swizzle)
      f16x8 ah[MI];
      #pragma unroll
      for (int i = 0; i < MI; i++)
        ah[i] = *(const f16x8*)(cur + (wm + i * 16 + fr) * 64 + col * 8);
      #pragma unroll
      for (int i = 0; i < MI; i++)
        #pragma unroll
        for (int j = 0; j < NJ; j++)
          acc[i][j] = __builtin_amdgcn_mfma_f32_16x16x32_f16(ah[i], bcur[ks * NJ + j], acc[i][j], 0, 0, 0);
    }
    __syncthreads();   // single barrier: my ds_reads of cur done; all waves' stage of nxt drained
    #pragma unroll
    for (int t = 0; t < 2 * NJ; t++) bcur[t] = bnxt[t];
  }
}

// C/D layout (measured m89/m91): col = lane&15, row = (lane>>4)*4 + reg

// R15: grid 1536 = 768 (m,z) pairs x 2 e-halves. XCD-tiled pair mapping kept
// from R12 (XCD t owns 8m x 12z: ~5MB L2 set). Block tile 128m x 64e; 4 waves
// of 64x32; LDS 32KB -> 5 blocks/CU (vs 3 grid-limited before).
__global__ __launch_bounds__(256) void gemm_qkv(
    const u16* __restrict__ xh, const u16* __restrict__ wT,
    const float* __restrict__ bq, const float* __restrict__ bk, const float* __restrict__ bv,
    u16* __restrict__ q, u16* __restrict__ k, u16* __restrict__ v) {
  __shared__ u16 As[128 * 64 * 2];
  const int wg = blockIdx.x;             // [0,1536)
  const int nh = wg & 1;                 // e-half
  const int pair = wg >> 1;              // [0,768)
  const int xcd = pair & 7;
  const int local = pair >> 3;           // [0,96)
  const int m_l = local & 7;             // 8 m-panels per tile
  const int z_l = local >> 3;            // 12 z-panels per tile
  const int m0 = (((xcd & 3) * 8) + m_l) * 128;
  const int z = (xcd >> 2) * 12 + z_l;   // proj*8 + h
  const int proj = z >> 3, h = z & 7;
  const int n0 = nh * 64;
  f32x4 acc[4][2];
  gemm_core<128, 2>(xh + (size_t)m0 * Kk,
                    wT + (size_t)z * (Ee * Kk) + (size_t)n0 * 8, As, acc);

  u16* dst = proj == 0 ? q : (proj == 1 ? k : v);
  const float* bias = proj == 0 ? bq : (proj == 1 ? bk : bv);
  const int wave = threadIdx.x >> 6, lane = threadIdx.x & 63;
  const int wm = (wave >> 1) * 64, wn = (wave & 1) * 32;
  const int cn = lane & 15, rq4 = (lane >> 4) * 4;
  #pragma unroll
  for (int j = 0; j < 2; j++) {
    const int e = n0 + wn + j * 16 + cn;
    const float bb = bias[h * Ee + e];
    #pragma unroll
    for (int i = 0; i < 4; i++) {
      #pragma unroll
      for (int r = 0; r < 4; r++) {
        const int m = m0 + wm + i * 16 + rq4 + r;     // m = b*S + s
        const int b = m >> 11, s = m & (Ss - 1);
        dst[(((size_t)(b * Hh + h)) * Ss + s) * Ee + e] = f2h(acc[i][j][r] + bb);
      }
    }
  }
}

// gemm_out: exact R10/R12 config (MT=64, NJ=4, grid 64x8) — best measured.
__global__ __launch_bounds__(256) void gemm_out(
    const u16* __restrict__ attn, const u16* __restrict__ woT,
    const float* __restrict__ bo, float* __restrict__ out) {
  __shared__ u16 As[64 * 64 * 2];
  const int m0 = blockIdx.x * 64;
  const int n0 = blockIdx.y * 128;
  f32x4 acc[2][4];
  gemm_core<64, 4>(attn + (size_t)m0 * Kk, woT + (size_t)blockIdx.y * 131072, As, acc);
  const int wave = threadIdx.x >> 6, lane = threadIdx.x & 63;
  const int wm = (wave >> 1) * 32, wn = (wave & 1) * 64;
  const int cn = lane & 15, rq4 = (lane >> 4) * 4;
  #pragma unroll
  for (int j = 0; j < 4; j++) {
    const int n = n0 + wn + j * 16 + cn;
    const float bb = bo[n];
    #pragma unroll
    for (int i = 0; i < 2; i++) {
      #pragma unroll
      for (int r = 0; r < 4; r++) {
        const int m = m0 + wm + i * 16 + rq4 + r;
        out[(size_t)m * Dd + n] = acc[i][j][r] + bb;
      }
    }
  }
}

// ---------------- attention: 4 s per wave (16-lane groups), dwordx4 loads ----------------
// Each wave = four 16-lane groups, one (b,h,s) each; lane lx owns elements
// e0 = lx*8 .. +7 (16B dwordx4 per row).
// R10: V rows loaded in j-order — pos is GROUP-UNIFORM, so all 16 lanes read the
// same 256B row segment (coalesced); weights redistributed on the shuffle side:
// gj[j] = __shfl(w, gbase|j) (uniform-index bpermute).
__global__ __launch_bounds__(256) void attn_kernel(
    const u16* __restrict__ q, const u16* __restrict__ k, const u16* __restrict__ v,
    const float* __restrict__ bk, const float* __restrict__ bv,
    const int* __restrict__ dil, u16* __restrict__ attn) {
  // XCD-contiguous swizzle: XCD i (= blockIdx%8 round-robin) gets a contiguous
  // blk range = 2 whole (b,h) panels -> disjoint ~3MB L2 working set per XCD.
  const int nblk = (Bb * Hh * Ss) / 16;           // 2048 blocks, 4 waves x 4 s
  const int blk = (blockIdx.x & 7) * (nblk / 8) + (blockIdx.x >> 3);
  const int wid = blk * 4 + (threadIdx.x >> 6);   // [0, 8192)
  const int lane = threadIdx.x & 63;
  const int grp = lane >> 4;                       // which s of this wave's 4
  const int lx = lane & 15;                        // lane within 16-group
  const int idx = wid * 4 + grp;                   // global (b,h,s) task
  const int s = idx & (Ss - 1);
  const int bh = idx >> 11;                        // b*H + h
  const int h = bh & 7, b = bh >> 3;
  const int d = dil[h];
  const size_t base = (size_t)bh * Ss * Ee;        // u16 elements
  const u16* kp = k + base;
  const u16* vp = v + base;
  const int e0 = lx * 8;
  const int off = (d * (KWW - 1)) >> 1;

  // q slice -> f32
  float qf[8];
  {
    uint4 qw = *(const uint4*)(q + base + (size_t)s * Ee + e0);
    qf[0] = h2f_lo(qw.x); qf[1] = h2f_hi(qw.x);
    qf[2] = h2f_lo(qw.y); qf[3] = h2f_hi(qw.y);
    qf[4] = h2f_lo(qw.z); qf[5] = h2f_hi(qw.z);
    qf[6] = h2f_lo(qw.w); qf[7] = h2f_hi(qw.w);
  }
  // bias slices (padded key/value = bias projection of zero-embedding)
  float bkf[8], bvf[8];
  {
    const float4 a0 = ((const float4*)(bk + h * Ee + e0))[0];
    const float4 a1 = ((const float4*)(bk + h * Ee + e0))[1];
    bkf[0]=a0.x; bkf[1]=a0.y; bkf[2]=a0.z; bkf[3]=a0.w;
    bkf[4]=a1.x; bkf[5]=a1.y; bkf[6]=a1.z; bkf[7]=a1.w;
    const float4 c0 = ((const float4*)(bv + h * Ee + e0))[0];
    const float4 c1 = ((const float4*)(bv + h * Ee + e0))[1];
    bvf[0]=c0.x; bvf[1]=c0.y; bvf[2]=c0.z; bvf[3]=c0.w;
    bvf[4]=c1.x; bvf[5]=c1.y; bvf[6]=c1.z; bvf[7]=c1.w;
  }
  float blog = 0.f;
  #pragma unroll
  for (int i = 0; i < 8; i++) blog += qf[i] * bkf[i];
  // packed f16 v-bias for OOB substitution at load time
  uint4 bvh;
  bvh.x = (uint32_t)f2h(bvf[0]) | ((uint32_t)f2h(bvf[1]) << 16);
  bvh.y = (uint32_t)f2h(bvf[2]) | ((uint32_t)f2h(bvf[3]) << 16);
  bvh.z = (uint32_t)f2h(bvf[4]) | ((uint32_t)f2h(bvf[5]) << 16);
  bvh.w = (uint32_t)f2h(bvf[6]) | ((uint32_t)f2h(bvf[7]) << 16);

  // ---- logit partials: lane lx holds partial (over its 8 elems) for ALL 16 j ----
  float logit[KWW];
  #pragma unroll
  for (int j = 0; j < KWW; j++) {
    const int pos = s + d * j - off;
    const int posc = min(max(pos, 0), Ss - 1);
    uint4 kw = *(const uint4*)(kp + (size_t)posc * Ee + e0);
    float t = qf[0] * h2f_lo(kw.x) + qf[1] * h2f_hi(kw.x)
            + qf[2] * h2f_lo(kw.y) + qf[3] * h2f_hi(kw.y)
            + qf[4] * h2f_lo(kw.z) + qf[5] * h2f_hi(kw.z)
            + qf[6] * h2f_lo(kw.w) + qf[7] * h2f_hi(kw.w);
    logit[j] = (pos >= 0 && pos < Ss) ? t : blog;
  }

  // ---- preload v rows in j order (pos group-uniform -> coalesced 256B/group) ----
  uint4 vrow[KWW];
  #pragma unroll
  for (int j = 0; j < KWW; j++) {
    const int pos = s + d * j - off;
    const int posc = min(max(pos, 0), Ss - 1);
    uint4 vw = *(const uint4*)(vp + (size_t)posc * Ee + e0);
    const bool ok = (pos >= 0) && (pos < Ss);
    vrow[j].x = ok ? vw.x : bvh.x;
    vrow[j].y = ok ? vw.y : bvh.y;
    vrow[j].z = ok ? vw.z : bvh.z;
    vrow[j].w = ok ? vw.w : bvh.w;
  }

  // ---- reduce-scatter within 16-lane groups: lane lx ends owning logit j = lx ----
  {
    const bool hi = (lx & 8) != 0;
    #pragma unroll
    for (int jj = 0; jj < 8; jj++) {
      float send = hi ? logit[jj] : logit[jj + 8];
      float recv = __shfl_xor(send, 8, 64);
      logit[jj] = (hi ? logit[jj + 8] : logit[jj]) + recv;
    }
  }
  {
    const bool hi = (lx & 4) != 0;
    #pragma unroll
    for (int jj = 0; jj < 4; jj++) {
      float send = hi ? logit[jj] : logit[jj + 4];
      float recv = __shfl_xor(send, 4, 64);
      logit[jj] = (hi ? logit[jj + 4] : logit[jj]) + recv;
    }
  }
  {
    const bool hi = (lx & 2) != 0;
    #pragma unroll
    for (int jj = 0; jj < 2; jj++) {
      float send = hi ? logit[jj] : logit[jj + 2];
      float recv = __shfl_xor(send, 2, 64);
      logit[jj] = (hi ? logit[jj + 2] : logit[jj]) + recv;
    }
  }
  float own;
  {
    const bool hi = (lx & 1) != 0;
    float send = hi ? logit[0] : logit[1];
    float recv = __shfl_xor(send, 1, 64);
    own = (hi ? logit[1] : logit[0]) + recv;   // own = full logit for j = lx
  }

  // ---- softmax over the 16 j's (one per lane in the group) ----
  float mx = own;
  mx = fmaxf(mx, __shfl_xor(mx, 1, 64));
  mx = fmaxf(mx, __shfl_xor(mx, 2, 64));
  mx = fmaxf(mx, __shfl_xor(mx, 4, 64));
  mx = fmaxf(mx, __shfl_xor(mx, 8, 64));
  float w = __expf(own - mx);
  float sum = w;
  sum += __shfl_xor(sum, 1, 64);
  sum += __shfl_xor(sum, 2, 64);
  sum += __shfl_xor(sum, 4, 64);
  sum += __shfl_xor(sum, 8, 64);
  w *= 1.0f / (sum * 11.313708498984760f);  // /Z /sqrt(E), post-softmax quirk

  // ---- gather per-j weights: gj[j] = w of lane (gbase+j); uniform-index bpermute ----
  const int gbase = lane & 48;
  float gj[KWW];
  #pragma unroll
  for (int j = 0; j < KWW; j++)
    gj[j] = __shfl(w, gbase | j, 64);

  // ---- PV: acc_e = sum_j gj[j] * v[j][e] ----
  float acc[8];
  #pragma unroll
  for (int i = 0; i < 8; i++) acc[i] = 0.f;
  #pragma unroll
  for (int j = 0; j < KWW; j++) {
    const float wt = gj[j];
    acc[0] += wt * h2f_lo(vrow[j].x);
    acc[1] += wt * h2f_hi(vrow[j].x);
    acc[2] += wt * h2f_lo(vrow[j].y);
    acc[3] += wt * h2f_hi(vrow[j].y);
    acc[4] += wt * h2f_lo(vrow[j].z);
    acc[5] += wt * h2f_hi(vrow[j].z);
    acc[6] += wt * h2f_lo(vrow[j].w);
    acc[7] += wt * h2f_hi(vrow[j].w);
  }

  // write fp16 attn as A-matrix [b*S+s][h*E+e], 16B per lane (coalesced per group)
  uint4 o;
  o.x = (uint32_t)f2h(acc[0]) | ((uint32_t)f2h(acc[1]) << 16);
  o.y = (uint32_t)f2h(acc[2]) | ((uint32_t)f2h(acc[3]) << 16);
  o.z = (uint32_t)f2h(acc[4]) | ((uint32_t)f2h(acc[5]) << 16);
  o.w = (uint32_t)f2h(acc[6]) | ((uint32_t)f2h(acc[7]) << 16);
  *(uint4*)(attn + (size_t)(b * Ss + s) * (Hh * Ee) + h * Ee + e0) = o;
}

// ---------------- launcher ----------------
extern "C" void kernel_launch(void* const* d_in, const int* in_sizes, int n_in,
                              void* d_out, int out_size, void* d_ws, size_t ws_size,
                              hipStream_t stream) {
  (void)in_sizes; (void)n_in; (void)out_size; (void)ws_size;
  const float* x  = (const float*)d_in[0];
  const float* Wq = (const float*)d_in[1];
  const float* bq = (const float*)d_in[2];
  const float* Wk = (const float*)d_in[3];
  const float* bk = (const float*)d_in[4];
  const float* Wv = (const float*)d_in[5];
  const float* bv = (const float*)d_in[6];
  const float* Wo = (const float*)d_in[7];
  const float* bo = (const float*)d_in[8];
  const int* dil  = (const int*)d_in[9];
  float* out = (float*)d_out;

  char* ws = (char*)d_ws;
  u16* xh  = (u16*)ws;  ws += (size_t)Mm * Kk * 2;             // 8 MB  [m][d] f16
  u16* wT  = (u16*)ws;  ws += (size_t)24 * Ee * Kk * 2;        // 6 MB  frag-major [z][kc][n][8]
  u16* woT = (u16*)ws;  ws += (size_t)Kk * Dd * 2;             // 2 MB  frag-major [nb][kc][nn][8]
  u16* q = (u16*)ws; ws += (size_t)Bb * Hh * Ss * Ee * 2;      // 8 MB each, f16 [bh][s][e]
  u16* k = (u16*)ws; ws += (size_t)Bb * Hh * Ss * Ee * 2;
  u16* v = (u16*)ws; ws += (size_t)Bb * Hh * Ss * Ee * 2;
  // attn (8 MB f16) aliases xh — dead after gemm_qkv (stream-ordered)
  u16* attn = xh;

  prep<<<8192, 256, 0, stream>>>(x, Wq, Wk, Wv, Wo, xh, wT, woT);
  gemm_qkv<<<1536, 256, 0, stream>>>(xh, wT, bq, bk, bv, q, k, v);
  attn_kernel<<<(Bb * Hh * Ss) / 16, 256, 0, stream>>>(q, k, v, bk, bv, dil, attn);
  gemm_out<<<dim3(Mm / 64, Dd / 128), 256, 0, stream>>>(attn, woT, bo, out);
}